// Round 1
// baseline (8351.274 us; speedup 1.0000x reference)
//
#include <hip/hip_runtime.h>
#include <math.h>

#define NRAYS 262144
#define MAXIT 192
#define NEARV 0.2f
#define FARV  2.0f
#define EPSV  0.001f

// ---------------------------------------------------------------------------
// Kernel 1: sphere march. Persistent waves, per-lane work-stealing via atomic
// counter. fp32 vector math; weights staged in LDS (wave-uniform broadcast
// reads). Only W2[:,0] is needed during marching.
// ---------------------------------------------------------------------------
__global__ __launch_bounds__(256, 3)
void march_kernel(const float* __restrict__ rays,
                  const float* __restrict__ W0, const float* __restrict__ b0,
                  const float* __restrict__ W1, const float* __restrict__ b1,
                  const float* __restrict__ W2, const float* __restrict__ b2,
                  float* __restrict__ t_out, int* __restrict__ hit_out,
                  int* __restrict__ counter)
{
    __shared__ float sW0[3 * 64];
    __shared__ float sb0[64];
    __shared__ float sW1[64 * 64];
    __shared__ float sb1[64];
    __shared__ float sW2c[64];
    __shared__ float sb2_0;

    const int tid = threadIdx.x;
    for (int i = tid; i < 3 * 64; i += 256) sW0[i] = W0[i];
    for (int i = tid; i < 64 * 64; i += 256) sW1[i] = W1[i];
    if (tid < 64) {
        sb0[tid] = b0[tid];
        sb1[tid] = b1[tid];
        sW2c[tid] = W2[tid * 33];   // column 0 of (64,33)
    }
    if (tid == 0) sb2_0 = b2[0];
    __syncthreads();

    float ox = 0.f, oy = 0.f, oz = 0.f, rdx = 0.f, rdy = 0.f, rdz = 0.f;
    float cd = 0.f;
    int ridx = -1, it = 0;
    bool has = false, hit = false, exhausted = false;

    while (true) {
        if (!has && !exhausted) {
            int idx = atomicAdd(counter, 1);
            if (idx < NRAYS) {
                const float* r = rays + (size_t)idx * 6;
                ox = r[0]; oy = r[1]; oz = r[2];
                rdx = r[3]; rdy = r[4]; rdz = r[5];
                cd = NEARV; it = 0; hit = false; has = true; ridx = idx;
            } else {
                exhausted = true;
            }
        }
        if (__ballot(has) == 0ull) break;

        // p = r_o + r_d * cd  (mul then add, matching numpy)
        const float px = ox + rdx * cd;
        const float py = oy + rdy * cd;
        const float pz = oz + rdz * cd;

        // h1 accumulates the layer-1 dot products (bias added at consumption,
        // matching numpy's (h0 @ W1) + b1 order).
        float h1[64];
        #pragma unroll
        for (int j = 0; j < 64; ++j) h1[j] = 0.f;

        for (int k = 0; k < 64; ++k) {
            float z = px * sW0[k] + py * sW0[64 + k] + pz * sW0[128 + k];
            z += sb0[k];
            const float a = fmaxf(z, 0.f);
            #pragma unroll
            for (int j = 0; j < 64; ++j) h1[j] = fmaf(a, sW1[k * 64 + j], h1[j]);
        }

        float d = 0.f;
        #pragma unroll
        for (int j = 0; j < 64; ++j)
            d = fmaf(fmaxf(h1[j] + sb1[j], 0.f), sW2c[j], d);
        d += sb2_0;

        if (has) {
            ++it;
            // rem implies cd <= FAR here (rem is cleared whenever cd > FAR)
            if (d < EPSV && cd <= FARV) hit = true;
            cd += d;                       // cd update happens before rem clears
            if (hit || cd > FARV || it >= MAXIT) {
                t_out[ridx] = cd;
                hit_out[ridx] = hit ? 1 : 0;
                has = false;
            }
        }
    }
}

// ---------------------------------------------------------------------------
// Kernel 2: shading. One thread per ray. Only hit rays produce output.
// Forward MLP (latent), hand-derived VJP for the normal, render MLP, sigmoid.
// ---------------------------------------------------------------------------
__global__ __launch_bounds__(256, 2)
void shade_kernel(const float* __restrict__ rays,
                  const float* __restrict__ W0, const float* __restrict__ b0,
                  const float* __restrict__ W1, const float* __restrict__ b1,
                  const float* __restrict__ W2, const float* __restrict__ b2,
                  const float* __restrict__ RW0, const float* __restrict__ Rb0,
                  const float* __restrict__ RW1, const float* __restrict__ Rb1,
                  const float* __restrict__ t_in, const int* __restrict__ hit_in,
                  float* __restrict__ out)
{
    __shared__ float sW0[3 * 64];
    __shared__ float sb0[64];
    __shared__ float sW1[64 * 64];
    __shared__ float sb1[64];
    __shared__ float sW2T[33 * 64];   // [c][j] = W2[j][c]
    __shared__ float sb2[33];
    __shared__ float sRW0T[64 * 48];  // [u][f] = RW0[f][u], padded 41->48
    __shared__ float sRb0[64];
    __shared__ float sRW1[64 * 3];
    __shared__ float sRb1[3];

    const int tid = threadIdx.x;
    for (int i = tid; i < 3 * 64; i += 256) sW0[i] = W0[i];
    for (int i = tid; i < 64 * 64; i += 256) sW1[i] = W1[i];
    for (int i = tid; i < 33 * 64; i += 256) {
        const int c = i >> 6, j = i & 63;
        sW2T[i] = W2[j * 33 + c];
    }
    for (int i = tid; i < 64 * 41; i += 256) {
        const int u = i / 41, f = i - u * 41;
        sRW0T[u * 48 + f] = RW0[f * 64 + u];
    }
    if (tid < 64) { sb0[tid] = b0[tid]; sb1[tid] = b1[tid]; sRb0[tid] = Rb0[tid]; }
    if (tid < 33) sb2[tid] = b2[tid];
    if (tid < 192) sRW1[tid] = RW1[tid];
    if (tid < 3) sRb1[tid] = Rb1[tid];
    __syncthreads();

    const int i = blockIdx.x * 256 + tid;
    const bool hit = hit_in[i] != 0;

    // Whole-wave skip when nobody hit.
    if (__ballot(hit) == 0ull) {
        out[i * 3 + 0] = 0.f;
        out[i * 3 + 1] = 0.f;
        out[i * 3 + 2] = 0.f;
        return;
    }

    const float* r = rays + (size_t)i * 6;
    const float cd = t_in[i];
    const float ox = r[0], oy = r[1], oz = r[2];
    const float dx = r[3], dy = r[4], dz = r[5];
    const float px = ox + dx * cd;
    const float py = oy + dy * cd;
    const float pz = oz + dz * cd;

    // ---- forward, layer 1 accumulation (h0 recomputed on the fly) ----
    float h1[64];
    #pragma unroll
    for (int j = 0; j < 64; ++j) h1[j] = 0.f;

    for (int k = 0; k < 64; ++k) {
        float z = px * sW0[k] + py * sW0[64 + k] + pz * sW0[128 + k];
        z += sb0[k];
        const float a = fmaxf(z, 0.f);
        #pragma unroll
        for (int j = 0; j < 64; ++j) h1[j] = fmaf(a, sW1[k * 64 + j], h1[j]);
    }
    // rh1 = relu(h1 + b1)  (overwrite in place; sign info preserved: rh1==0 <=> z1<=0)
    #pragma unroll
    for (int j = 0; j < 64; ++j) h1[j] = fmaxf(h1[j] + sb1[j], 0.f);

    // ---- latent = out[:,1:33] ----
    float lat[32];
    #pragma unroll
    for (int c = 1; c < 33; ++c) {
        float acc = 0.f;
        #pragma unroll
        for (int j = 0; j < 64; ++j) acc = fmaf(h1[j], sW2T[c * 64 + j], acc);
        lat[c - 1] = acc + sb2[c];
    }

    // ---- backward: gz1 = (z1>0) ? W2[:,0] : 0  (overwrite h1) ----
    #pragma unroll
    for (int j = 0; j < 64; ++j) h1[j] = (h1[j] > 0.f) ? sW2T[j] : 0.f;

    float nx = 0.f, ny = 0.f, nz = 0.f;
    for (int k = 0; k < 64; ++k) {
        float z = px * sW0[k] + py * sW0[64 + k] + pz * sW0[128 + k];
        z += sb0[k];
        float g = 0.f;
        #pragma unroll
        for (int j = 0; j < 64; ++j) g = fmaf(h1[j], sW1[k * 64 + j], g);
        if (z > 0.f) {
            nx = fmaf(g, sW0[k], nx);
            ny = fmaf(g, sW0[64 + k], ny);
            nz = fmaf(g, sW0[128 + k], nz);
        }
    }
    if (!hit) { nx = 0.f; ny = 0.f; nz = 0.f; }

    // ---- render MLP: feat(41) = [pts, r_d, nrm, latent] ----
    float r0 = 0.f, r1 = 0.f, r2 = 0.f;
    for (int u = 0; u < 64; ++u) {
        const float* w = &sRW0T[u * 48];
        float a = px * w[0] + py * w[1] + pz * w[2];
        a = fmaf(dx, w[3], a); a = fmaf(dy, w[4], a); a = fmaf(dz, w[5], a);
        a = fmaf(nx, w[6], a); a = fmaf(ny, w[7], a); a = fmaf(nz, w[8], a);
        #pragma unroll
        for (int q = 0; q < 32; ++q) a = fmaf(lat[q], w[9 + q], a);
        a += sRb0[u];
        const float ru = fmaxf(a, 0.f);
        r0 = fmaf(ru, sRW1[u * 3 + 0], r0);
        r1 = fmaf(ru, sRW1[u * 3 + 1], r1);
        r2 = fmaf(ru, sRW1[u * 3 + 2], r2);
    }
    r0 += sRb1[0]; r1 += sRb1[1]; r2 += sRb1[2];

    const float o0 = 1.f / (1.f + expf(-r0));
    const float o1 = 1.f / (1.f + expf(-r1));
    const float o2 = 1.f / (1.f + expf(-r2));

    out[i * 3 + 0] = hit ? o0 : 0.f;
    out[i * 3 + 1] = hit ? o1 : 0.f;
    out[i * 3 + 2] = hit ? o2 : 0.f;
}

extern "C" void kernel_launch(void* const* d_in, const int* in_sizes, int n_in,
                              void* d_out, int out_size, void* d_ws, size_t ws_size,
                              hipStream_t stream) {
    const float* rays = (const float*)d_in[0];
    const float* W0   = (const float*)d_in[1];
    const float* b0   = (const float*)d_in[2];
    const float* W1   = (const float*)d_in[3];
    const float* b1   = (const float*)d_in[4];
    const float* W2   = (const float*)d_in[5];
    const float* b2   = (const float*)d_in[6];
    const float* RW0  = (const float*)d_in[7];
    const float* Rb0  = (const float*)d_in[8];
    const float* RW1  = (const float*)d_in[9];
    const float* Rb1  = (const float*)d_in[10];

    // Workspace layout: t (N floats) | hit (N ints) | counter (1 int)
    float* t_ws  = (float*)d_ws;
    int* hit_ws  = (int*)d_ws + NRAYS;
    int* ctr     = (int*)d_ws + 2 * NRAYS;

    hipMemsetAsync(ctr, 0, sizeof(int), stream);

    // Persistent march: ~196K lanes for 262K rays (3 blocks/CU at 3 waves/SIMD)
    march_kernel<<<768, 256, 0, stream>>>(rays, W0, b0, W1, b1, W2, b2,
                                          t_ws, hit_ws, ctr);

    shade_kernel<<<NRAYS / 256, 256, 0, stream>>>(rays, W0, b0, W1, b1, W2, b2,
                                                  RW0, Rb0, RW1, Rb1,
                                                  t_ws, hit_ws, (float*)d_out);
}

// Round 2
// 6806.918 us; speedup vs baseline: 1.2269x; 1.2269x over previous
//
#include <hip/hip_runtime.h>
#include <math.h>

#define NRAYS 262144
#define MAXIT 192
#define NEARV 0.2f
#define FARV  2.0f
#define EPSV  0.001f

// ---------------------------------------------------------------------------
// Kernel 1: sphere march. Persistent waves + atomic work-stealing.
// All weight reads are wave-uniform loads from const __restrict__ global
// pointers -> compiler selects scalar s_load (SGPR-held weights, scalar
// cache). Zero LDS in this kernel: the R1 profile showed the CU-shared LDS
// broadcast datapath (not the VALU) was the bottleneck (VALUBusy 33%).
// Arithmetic is bit-identical to the R1 passing kernel.
// ---------------------------------------------------------------------------
__global__ __launch_bounds__(256, 4)
void march_kernel(const float* __restrict__ rays,
                  const float* __restrict__ W0, const float* __restrict__ b0,
                  const float* __restrict__ W1, const float* __restrict__ b1,
                  const float* __restrict__ W2, const float* __restrict__ b2,
                  float* __restrict__ t_out, int* __restrict__ hit_out,
                  int* __restrict__ counter)
{
    float ox = 0.f, oy = 0.f, oz = 0.f, rdx = 0.f, rdy = 0.f, rdz = 0.f;
    float cd = 0.f;
    int ridx = -1, it = 0;
    bool has = false, hit = false, exhausted = false;

    const float b2_0 = b2[0];

    while (true) {
        if (!has && !exhausted) {
            int idx = atomicAdd(counter, 1);
            if (idx < NRAYS) {
                const float* r = rays + (size_t)idx * 6;
                ox = r[0]; oy = r[1]; oz = r[2];
                rdx = r[3]; rdy = r[4]; rdz = r[5];
                cd = NEARV; it = 0; hit = false; has = true; ridx = idx;
            } else {
                exhausted = true;
            }
        }
        if (__ballot(has) == 0ull) break;

        // p = r_o + r_d * cd  (mul then add, matching numpy)
        const float px = ox + rdx * cd;
        const float py = oy + rdy * cd;
        const float pz = oz + rdz * cd;

        float h1[64];
        #pragma unroll
        for (int j = 0; j < 64; ++j) h1[j] = 0.f;

        for (int k = 0; k < 64; ++k) {
            // uniform indices -> scalar loads
            float z = px * W0[k] + py * W0[64 + k] + pz * W0[128 + k];
            z += b0[k];
            const float a = fmaxf(z, 0.f);
            #pragma unroll
            for (int j = 0; j < 64; ++j) h1[j] = fmaf(a, W1[k * 64 + j], h1[j]);
        }

        float d = 0.f;
        #pragma unroll
        for (int j = 0; j < 64; ++j)
            d = fmaf(fmaxf(h1[j] + b1[j], 0.f), W2[j * 33], d);
        d += b2_0;

        if (has) {
            ++it;
            if (d < EPSV && cd <= FARV) hit = true;
            cd += d;
            if (hit || cd > FARV || it >= MAXIT) {
                t_out[ridx] = cd;
                hit_out[ridx] = hit ? 1 : 0;
                has = false;
            }
        }
    }
}

// ---------------------------------------------------------------------------
// Kernel 2: shading. One thread per ray. Only hit rays produce output.
// (Unchanged from R1 passing version — bit-exact.)
// ---------------------------------------------------------------------------
__global__ __launch_bounds__(256, 2)
void shade_kernel(const float* __restrict__ rays,
                  const float* __restrict__ W0, const float* __restrict__ b0,
                  const float* __restrict__ W1, const float* __restrict__ b1,
                  const float* __restrict__ W2, const float* __restrict__ b2,
                  const float* __restrict__ RW0, const float* __restrict__ Rb0,
                  const float* __restrict__ RW1, const float* __restrict__ Rb1,
                  const float* __restrict__ t_in, const int* __restrict__ hit_in,
                  float* __restrict__ out)
{
    __shared__ float sW0[3 * 64];
    __shared__ float sb0[64];
    __shared__ float sW1[64 * 64];
    __shared__ float sb1[64];
    __shared__ float sW2T[33 * 64];   // [c][j] = W2[j][c]
    __shared__ float sb2[33];
    __shared__ float sRW0T[64 * 48];  // [u][f] = RW0[f][u], padded 41->48
    __shared__ float sRb0[64];
    __shared__ float sRW1[64 * 3];
    __shared__ float sRb1[3];

    const int tid = threadIdx.x;
    for (int i = tid; i < 3 * 64; i += 256) sW0[i] = W0[i];
    for (int i = tid; i < 64 * 64; i += 256) sW1[i] = W1[i];
    for (int i = tid; i < 33 * 64; i += 256) {
        const int c = i >> 6, j = i & 63;
        sW2T[i] = W2[j * 33 + c];
    }
    for (int i = tid; i < 64 * 41; i += 256) {
        const int u = i / 41, f = i - u * 41;
        sRW0T[u * 48 + f] = RW0[f * 64 + u];
    }
    if (tid < 64) { sb0[tid] = b0[tid]; sb1[tid] = b1[tid]; sRb0[tid] = Rb0[tid]; }
    if (tid < 33) sb2[tid] = b2[tid];
    if (tid < 192) sRW1[tid] = RW1[tid];
    if (tid < 3) sRb1[tid] = Rb1[tid];
    __syncthreads();

    const int i = blockIdx.x * 256 + tid;
    const bool hit = hit_in[i] != 0;

    // Whole-wave skip when nobody hit.
    if (__ballot(hit) == 0ull) {
        out[i * 3 + 0] = 0.f;
        out[i * 3 + 1] = 0.f;
        out[i * 3 + 2] = 0.f;
        return;
    }

    const float* r = rays + (size_t)i * 6;
    const float cd = t_in[i];
    const float ox = r[0], oy = r[1], oz = r[2];
    const float dx = r[3], dy = r[4], dz = r[5];
    const float px = ox + dx * cd;
    const float py = oy + dy * cd;
    const float pz = oz + dz * cd;

    // ---- forward, layer 1 accumulation (h0 recomputed on the fly) ----
    float h1[64];
    #pragma unroll
    for (int j = 0; j < 64; ++j) h1[j] = 0.f;

    for (int k = 0; k < 64; ++k) {
        float z = px * sW0[k] + py * sW0[64 + k] + pz * sW0[128 + k];
        z += sb0[k];
        const float a = fmaxf(z, 0.f);
        #pragma unroll
        for (int j = 0; j < 64; ++j) h1[j] = fmaf(a, sW1[k * 64 + j], h1[j]);
    }
    // rh1 = relu(h1 + b1)  (overwrite in place; rh1==0 <=> z1<=0)
    #pragma unroll
    for (int j = 0; j < 64; ++j) h1[j] = fmaxf(h1[j] + sb1[j], 0.f);

    // ---- latent = out[:,1:33] ----
    float lat[32];
    #pragma unroll
    for (int c = 1; c < 33; ++c) {
        float acc = 0.f;
        #pragma unroll
        for (int j = 0; j < 64; ++j) acc = fmaf(h1[j], sW2T[c * 64 + j], acc);
        lat[c - 1] = acc + sb2[c];
    }

    // ---- backward: gz1 = (z1>0) ? W2[:,0] : 0  (overwrite h1) ----
    #pragma unroll
    for (int j = 0; j < 64; ++j) h1[j] = (h1[j] > 0.f) ? sW2T[j] : 0.f;

    float nx = 0.f, ny = 0.f, nz = 0.f;
    for (int k = 0; k < 64; ++k) {
        float z = px * sW0[k] + py * sW0[64 + k] + pz * sW0[128 + k];
        z += sb0[k];
        float g = 0.f;
        #pragma unroll
        for (int j = 0; j < 64; ++j) g = fmaf(h1[j], sW1[k * 64 + j], g);
        if (z > 0.f) {
            nx = fmaf(g, sW0[k], nx);
            ny = fmaf(g, sW0[64 + k], ny);
            nz = fmaf(g, sW0[128 + k], nz);
        }
    }
    if (!hit) { nx = 0.f; ny = 0.f; nz = 0.f; }

    // ---- render MLP: feat(41) = [pts, r_d, nrm, latent] ----
    float r0 = 0.f, r1 = 0.f, r2 = 0.f;
    for (int u = 0; u < 64; ++u) {
        const float* w = &sRW0T[u * 48];
        float a = px * w[0] + py * w[1] + pz * w[2];
        a = fmaf(dx, w[3], a); a = fmaf(dy, w[4], a); a = fmaf(dz, w[5], a);
        a = fmaf(nx, w[6], a); a = fmaf(ny, w[7], a); a = fmaf(nz, w[8], a);
        #pragma unroll
        for (int q = 0; q < 32; ++q) a = fmaf(lat[q], w[9 + q], a);
        a += sRb0[u];
        const float ru = fmaxf(a, 0.f);
        r0 = fmaf(ru, sRW1[u * 3 + 0], r0);
        r1 = fmaf(ru, sRW1[u * 3 + 1], r1);
        r2 = fmaf(ru, sRW1[u * 3 + 2], r2);
    }
    r0 += sRb1[0]; r1 += sRb1[1]; r2 += sRb1[2];

    const float o0 = 1.f / (1.f + expf(-r0));
    const float o1 = 1.f / (1.f + expf(-r1));
    const float o2 = 1.f / (1.f + expf(-r2));

    out[i * 3 + 0] = hit ? o0 : 0.f;
    out[i * 3 + 1] = hit ? o1 : 0.f;
    out[i * 3 + 2] = hit ? o2 : 0.f;
}

extern "C" void kernel_launch(void* const* d_in, const int* in_sizes, int n_in,
                              void* d_out, int out_size, void* d_ws, size_t ws_size,
                              hipStream_t stream) {
    const float* rays = (const float*)d_in[0];
    const float* W0   = (const float*)d_in[1];
    const float* b0   = (const float*)d_in[2];
    const float* W1   = (const float*)d_in[3];
    const float* b1   = (const float*)d_in[4];
    const float* W2   = (const float*)d_in[5];
    const float* b2   = (const float*)d_in[6];
    const float* RW0  = (const float*)d_in[7];
    const float* Rb0  = (const float*)d_in[8];
    const float* RW1  = (const float*)d_in[9];
    const float* Rb1  = (const float*)d_in[10];

    // Workspace layout: t (N floats) | hit (N ints) | counter (1 int)
    float* t_ws  = (float*)d_ws;
    int* hit_ws  = (int*)d_ws + NRAYS;
    int* ctr     = (int*)d_ws + 2 * NRAYS;

    hipMemsetAsync(ctr, 0, sizeof(int), stream);

    // Persistent march: 4 blocks/CU co-resident, no LDS.
    march_kernel<<<1024, 256, 0, stream>>>(rays, W0, b0, W1, b1, W2, b2,
                                           t_ws, hit_ws, ctr);

    shade_kernel<<<NRAYS / 256, 256, 0, stream>>>(rays, W0, b0, W1, b1, W2, b2,
                                                  RW0, Rb0, RW1, Rb1,
                                                  t_ws, hit_ws, (float*)d_out);
}